// Round 7
// baseline (162.763 us; speedup 1.0000x reference)
//
#include <hip/hip_runtime.h>

// Fused UpFIRDn2d via banded MFMA chain: crop(1) -> +bias -> repeat-up x2 ->
// sep 12-tap FIR -> leaky_relu(0.2)*sqrt(2) -> sep 12-tap FIR -> down x2.
// x: (8,64,130,130) f32; out: (8,64,128,128) f32.
//
// Round 7: 2 planes/block + transpose-free chain + preloaded constants.
// Stage algebra (separable convs reordered; constants IDENTICAL to round 6 -
// A/B frags share the same lane mapping on 16x16x32):
//   S1 : B1t[qq][r] = (X * Gt)^T          A=X (LDS), B=GtB      M48t N80 K32
//   S2': U[pp][qq]  = leaky(B1t * G2t)^T.. A=B1t, B=G2A         (K=32 banded)
//   S3': V[j][pp]   = (U * D2t)^T         A=U,   B=D2B          (K=64 banded)
//   S4': Out[a][j]  = DA * V              A=DA,  B=V            (K=64 banded)
// Every LDS write is a contiguous b64 (C/D rows), every LDS read a b128.
// Edge clip folded into DA variants (by, H-down) / D2B variants (bx, W-down).

#define GAIN_C 1.4142135623730951f
#define NEG_C ((0.2f - 1.0f) * GAIN_C)

typedef short v8s __attribute__((ext_vector_type(8)));
typedef float v4f __attribute__((ext_vector_type(4)));

__device__ __forceinline__ int f2bf(float f) {   // fp32 -> bf16 bits (RNE)
    unsigned u = __float_as_uint(f);
    return (int)((u + 0x7FFFu + ((u >> 16) & 1u)) >> 16) & 0xFFFF;
}
__device__ __forceinline__ int pack_bf2(float a, float b) {
#if __has_builtin(__builtin_amdgcn_cvt_pk_bf16_f32)
    typedef __bf16 bf2 __attribute__((ext_vector_type(2)));
    bf2 r = __builtin_amdgcn_cvt_pk_bf16_f32(a, b);
    int o; __builtin_memcpy(&o, &r, 4); return o;
#else
    return f2bf(a) | (f2bf(b) << 16);
#endif
}

// band(x, q): up-conv weight linking local x index x to local up index q.
__device__ float band(int x, int q, const float* fu) {
    if (q >= 74 || x >= 43 || x < 0) return 0.f;
    int p = q >> 1, d = x - p;
    if (q & 1) {
        if (d < 0 || d > 6) return 0.f;
        if (d == 0) return fu[0];
        if (d == 6) return fu[11];
        return fu[2 * d - 1] + fu[2 * d];
    } else {
        if (d < 0 || d > 5) return 0.f;
        return fu[2 * d] + fu[2 * d + 1];
    }
}
// dband(o, q, v): down-conv weight, out index o, up index q; variant v:
// 0 = first tile (zero q<5), 2 = last tile (zero q>=69).
__device__ float dband(int o, int q, int v, const float* fd) {
    if (q >= 74 || q < 0) return 0.f;
    if (v == 0 && q < 5) return 0.f;
    if (v == 2 && q >= 69) return 0.f;
    int k = q - 2 * o;
    if (k < 0 || k > 11) return 0.f;
    return fd[k];
}

// ws layout (bf16): GtB 5x512 @0 | G2A 5x512 @2560 |
// DA 3var x (2mt x 2kt) x512 @5120 | D2B 3var x (2nt x 2kt) x512 @11264.
// Total 17408 shorts. K-window starts: S1/S2 k0 = min(8*t,16);
// S3/S4 k0 = t ? 16 : 0.  (UNCHANGED from round 6 - verified passing.)
__global__ __launch_bounds__(256) void build_consts(
    const float* __restrict__ fu, const float* __restrict__ fd,
    short* __restrict__ ws)
{
    int idx = blockIdx.x * 256 + threadIdx.x;   // grid covers 17408 exactly
    int l = (idx >> 3) & 63, j = idx & 7;
    int l15 = l & 15, kq = (l >> 4) * 8 + j;
    float val;
    if (idx < 2560) {                         // GtB: B-op, frag = nt
        int nt = idx >> 9;
        int k0 = 8 * nt < 16 ? 8 * nt : 16;
        val = band(k0 + kq, 16 * nt + l15, fu);
    } else if (idx < 5120) {                  // G2A: frag = pp-tile
        int mt = (idx - 2560) >> 9;
        int k0 = 8 * mt < 16 ? 8 * mt : 16;
        val = band(k0 + kq, 16 * mt + l15, fu);
    } else if (idx < 11264) {                 // DA: frag = (v, mt*2+kt)
        int rel = idx - 5120;
        int v = rel >> 11, fi = (rel & 2047) >> 9;
        int mt = fi >> 1, kt = fi & 1;
        int pp = (mt ? 16 : 0) + 32 * kt + kq;
        val = dband(16 * mt + l15, pp, v, fd);
    } else {                                  // D2B: frag = (v, nt*2+kt)
        int rel = idx - 11264;
        int v = rel >> 11, fi = (rel & 2047) >> 9;
        int nt = fi >> 1, kt = fi & 1;
        int qq = (nt ? 16 : 0) + 32 * kt + kq;
        val = dband(16 * nt + l15, qq, v, fd);
    }
    ws[idx] = (short)f2bf(val);
}

#define XP2 48    // Xl  [48 r][48 c]
#define BP2 48    // B1t [80 qq][48 r]
#define UP2 88    // U   [80 pp][88 qq] and V [32 j][88 pp]; stride 44 ints -> 2-way
#define RSZ 13184 // per-plane region (shorts): Xl/V @0 (<=6144), U @6144 (7040)

__global__ __launch_bounds__(320, 4) void upfirdn_mfma(
    const float* __restrict__ xin_all,
    const float* __restrict__ bias,
    const short* __restrict__ cws,
    float* __restrict__ out)
{
    __shared__ __align__(16) short SH[2 * RSZ];   // 52736 B -> 3 blocks/CU

    const int tid  = threadIdx.x;
    const int lane = tid & 63, w = tid >> 6;
    const int l15  = lane & 15, q4 = lane >> 4;
    const int bx = blockIdx.x, by = blockIdx.y;
    const int bc0 = blockIdx.z * 2;
    const int i0 = by * 32, j0 = bx * 32;

    // ---- preload ALL constant fragments (independent of X; hides under P0) ----
    const short* DAv  = cws + 5120  + ((by == 0) ? 0 : (by == 3) ? 2 : 1) * 2048;
    const short* D2Bv = cws + 11264 + ((bx == 0) ? 0 : (bx == 3) ? 2 : 1) * 2048;
    v8s gtb = *(const v8s*)&cws[w * 512 + lane * 8];            // S1 B-frag (nt=w)
    v8s g2a = *(const v8s*)&cws[2560 + w * 512 + lane * 8];     // S2' B-frag (ppt=w)
    v8s d2b[4];
#pragma unroll
    for (int f = 0; f < 4; ++f) d2b[f] = *(const v8s*)&D2Bv[f * 512 + lane * 8];
    const int mt4 = (w >> 1) & 1;                               // S4' a-tile
    v8s da0 = *(const v8s*)&DAv[(mt4 * 2 + 0) * 512 + lane * 8];
    v8s da1 = *(const v8s*)&DAv[(mt4 * 2 + 1) * 512 + lane * 8];

    // ---- P0: stage X for both planes (crop +1, +bias); pads computed zero ----
    {
        const float* xp0 = xin_all + (size_t)bc0 * 16900;
        const float* xp1 = xp0 + 16900;
        const float bv0 = bias[bc0 & 63], bv1 = bias[(bc0 + 1) & 63];
        const bool rowInt = (by == 1) | (by == 2);
        const bool colInt = (bx == 1) | (bx == 2);
        int* Xli = (int*)SH;
        for (int idx = tid; idx < 2304; idx += 320) {
            int pl = (idx >= 1152);
            int ii = idx - (pl ? 1152 : 0);
            int r = ii / 24, cp = ii - r * 24;
            int gr = i0 - 5 + r;
            const float* xp = pl ? xp1 : xp0;
            const float bv = pl ? bv1 : bv0;
            float f0 = 0.f, f1 = 0.f;
            bool rok = (r < 43) && (rowInt || (unsigned)gr < 128u);
            if (rok && cp < 22) {
                int gc0 = j0 - 5 + 2 * cp;
                const float* rowp = xp + (gr + 1) * 130 + 1;
                if (colInt) {   // (gr+1)*130 + 1 + gc0 is even -> float2 aligned
                    float2 v = *(const float2*)(rowp + gc0);
                    f0 = v.x + bv;
                    f1 = (cp < 21) ? v.y + bv : 0.f;
                } else {
                    if ((unsigned)gc0 < 128u) f0 = rowp[gc0] + bv;
                    if (cp < 21 && (unsigned)(gc0 + 1) < 128u)
                        f1 = rowp[gc0 + 1] + bv;
                }
            }
            Xli[pl * (RSZ / 2) + r * 24 + cp] = pack_bf2(f0, f1);
        }
    }
    __syncthreads();

    const int k0u = (8 * w < 16) ? 8 * w : 16;   // banded K start for S1/S2'

    // ---- S1: B1t[qq][r], wave w = qq-tile nt. A=Xl, B=gtb. 6 MFMA/wave. ----
#pragma unroll
    for (int pl = 0; pl < 2; ++pl) {
        const short* Xl  = SH + pl * RSZ;
        short*       B1t = SH + pl * RSZ + 2304;
#pragma unroll
        for (int mt = 0; mt < 3; ++mt) {
            v8s a = *(const v8s*)&Xl[(16 * mt + l15) * XP2 + k0u + q4 * 8];
            v4f acc = {0.f, 0.f, 0.f, 0.f};
            acc = __builtin_amdgcn_mfma_f32_16x16x32_bf16(a, gtb, acc, 0, 0, 0);
            // C: col qq=16w+l15 (frag nt=w), rows r = 16mt + q4*4 + i
            *(int2*)&B1t[(16 * w + l15) * BP2 + 16 * mt + q4 * 4] =
                make_int2(pack_bf2(acc[0], acc[1]), pack_bf2(acc[2], acc[3]));
        }
    }
    __syncthreads();

    // ---- S2': U[pp][qq] = leaky((B1t*G2t)), wave w = pp-tile. 10 MFMA/wave. ----
#pragma unroll
    for (int pl = 0; pl < 2; ++pl) {
        const short* B1t = SH + pl * RSZ + 2304;
        short*       U   = SH + pl * RSZ + 6144;
#pragma unroll
        for (int mt = 0; mt < 5; ++mt) {     // qq-tiles
            v8s a = *(const v8s*)&B1t[(16 * mt + l15) * BP2 + k0u + q4 * 8];
            v4f acc = {0.f, 0.f, 0.f, 0.f};
            acc = __builtin_amdgcn_mfma_f32_16x16x32_bf16(a, g2a, acc, 0, 0, 0);
#pragma unroll
            for (int i = 0; i < 4; ++i)
                acc[i] = GAIN_C * acc[i] + NEG_C * fminf(acc[i], 0.f);
            // C: col pp=16w+l15, rows qq = 16mt + q4*4 + i -> U row-major b64
            *(int2*)&U[(16 * w + l15) * UP2 + 16 * mt + q4 * 4] =
                make_int2(pack_bf2(acc[0], acc[1]), pack_bf2(acc[2], acc[3]));
        }
    }
    __syncthreads();

    // ---- S3': V[j][pp] = (U*D2t)^T, wave w = pp-tile mt. 8 MFMA/wave. ----
#pragma unroll
    for (int pl = 0; pl < 2; ++pl) {
        const short* U = SH + pl * RSZ + 6144;
        short*       V = SH + pl * RSZ;                  // aliases dead Xl/B1t
#pragma unroll
        for (int nt = 0; nt < 2; ++nt) {     // j-tiles
            const int k0 = nt ? 16 : 0;
            v4f acc = {0.f, 0.f, 0.f, 0.f};
#pragma unroll
            for (int kt = 0; kt < 2; ++kt) {
                v8s a = *(const v8s*)&U[(16 * w + l15) * UP2 + k0 + 32 * kt + q4 * 8];
                acc = __builtin_amdgcn_mfma_f32_16x16x32_bf16(a, d2b[nt * 2 + kt],
                                                              acc, 0, 0, 0);
            }
            // C: col j=16nt+l15, rows pp = 16w + q4*4 + i -> V[j][pp] b64
            *(int2*)&V[(16 * nt + l15) * UP2 + 16 * w + q4 * 4] =
                make_int2(pack_bf2(acc[0], acc[1]), pack_bf2(acc[2], acc[3]));
        }
    }
    __syncthreads();

    // ---- S4': Out = DA * V. Waves 0..3: (mt=w>>1, nt=w&1), both planes. ----
    if (w < 4) {
        const int mt = w >> 1, nt = w & 1;    // mt == mt4
        const int k0 = mt ? 16 : 0;
#pragma unroll
        for (int pl = 0; pl < 2; ++pl) {
            const short* V = SH + pl * RSZ;
            v4f acc = {0.f, 0.f, 0.f, 0.f};
            v8s b0 = *(const v8s*)&V[(16 * nt + l15) * UP2 + k0 + q4 * 8];
            v8s b1 = *(const v8s*)&V[(16 * nt + l15) * UP2 + k0 + 32 + q4 * 8];
            acc = __builtin_amdgcn_mfma_f32_16x16x32_bf16(da0, b0, acc, 0, 0, 0);
            acc = __builtin_amdgcn_mfma_f32_16x16x32_bf16(da1, b1, acc, 0, 0, 0);
            float* op = out + (size_t)(bc0 + pl) * 16384
                      + (size_t)(i0 + 16 * mt + q4 * 4) * 128 + (j0 + 16 * nt + l15);
#pragma unroll
            for (int i = 0; i < 4; ++i) op[i * 128] = acc[i];
        }
    }
}

extern "C" void kernel_launch(void* const* d_in, const int* in_sizes, int n_in,
                              void* d_out, int out_size, void* d_ws, size_t ws_size,
                              hipStream_t stream) {
    const float* x  = (const float*)d_in[0];
    const float* bs = (const float*)d_in[1];
    const float* fu = (const float*)d_in[2];
    const float* fd = (const float*)d_in[3];
    float* outp = (float*)d_out;
    short* ws = (short*)d_ws;

    build_consts<<<68, 256, 0, stream>>>(fu, fd, ws);      // 17408 elems
    upfirdn_mfma<<<dim3(4, 4, 256), 320, 0, stream>>>(x, bs, ws, outp);
}